// Round 2
// baseline (1521.411 us; speedup 1.0000x reference)
//
#include <hip/hip_runtime.h>
#include <hip/hip_bf16.h>

#define NTOK 1024
#define NB   64
#define CD   256
#define NHEAD 8
#define HDIM 32
#define NS 256   // 16*16 reduced tokens
#define NBC  16384  // NB*CD

// ---- trig tables: t1[1024][4] (cos a, sin a, cos b, sin b), t2[256][4] ----
__global__ __launch_bounds__(256) void k_trig(float* __restrict__ t1, float* __restrict__ t2){
  int n = blockIdx.x*256 + threadIdx.x;           // 4 blocks -> n in [0,1024)
  const float c = 1.57079632679489662f;
  float aa = c * (float)(n >> 5) / 32.0f;
  float bb = c * (float)(n & 31) / 32.0f;
  t1[n*4+0]=cosf(aa); t1[n*4+1]=sinf(aa); t1[n*4+2]=cosf(bb); t1[n*4+3]=sinf(bb);
  if (n < 256){
    float a2 = c * (float)(n >> 4) / 16.0f;
    float b2 = c * (float)(n & 15) / 16.0f;
    t2[n*4+0]=cosf(a2); t2[n*4+1]=sinf(a2); t2[n*4+2]=cosf(b2); t2[n*4+3]=sinf(b2);
  }
}

// ---- SE: partial mean over n (4 quarters per b) ----
__global__ __launch_bounds__(256) void k_semean(const float* __restrict__ q, float* __restrict__ part){
  int b = blockIdx.x >> 2, qr = blockIdx.x & 3;
  int c = threadIdx.x;
  const float* qp = q + (qr*256)*NBC + b*CD + c;
  float s0=0.f,s1=0.f,s2=0.f,s3=0.f;
  for (int n=0;n<256;n+=4){
    s0 += qp[(n  )*NBC];
    s1 += qp[(n+1)*NBC];
    s2 += qp[(n+2)*NBC];
    s3 += qp[(n+3)*NBC];
  }
  part[blockIdx.x*256 + c] = (s0+s1)+(s2+s3);
}

// ---- SE MLP: se = sigmoid(relu(mean @ w1^T) @ w2^T), per b ----
__global__ __launch_bounds__(256) void k_semlp(const float* __restrict__ part, const float* __restrict__ w1,
                                               const float* __restrict__ w2, float* __restrict__ se){
  __shared__ float sm[256];
  __shared__ float s1s[128];
  int b = blockIdx.x, t = threadIdx.x;
  float s = (part[(b*4+0)*256+t]+part[(b*4+1)*256+t])+(part[(b*4+2)*256+t]+part[(b*4+3)*256+t]);
  sm[t] = s*(1.0f/1024.0f);
  __syncthreads();
  if (t < 128){
    float a = 0.f;
    const float* wr = w1 + t*256;
    for (int c=0;c<256;c+=4){
      float4 wf = *(const float4*)(wr+c);
      a += sm[c]*wf.x + sm[c+1]*wf.y + sm[c+2]*wf.z + sm[c+3]*wf.w;
    }
    s1s[t] = fmaxf(a, 0.f);
  }
  __syncthreads();
  float a = 0.f;
  const float* wr2 = w2 + t*128;
  for (int c=0;c<128;c+=4){
    float4 wf = *(const float4*)(wr2+c);
    a += s1s[c]*wf.x + s1s[c+1]*wf.y + s1s[c+2]*wf.z + s1s[c+3]*wf.w;
  }
  se[b*256+t] = 1.0f/(1.0f+expf(-a));
}

// ---- conv 2x2 stride 2 as GEMM: xr[b*256 + hs*16 + ws][o] ----
// sr_w layout: [o][cin][kh][kw] (256,256,2,2)
__global__ __launch_bounds__(256) void k_conv(const float* __restrict__ xf, const float* __restrict__ srw,
                                              const float* __restrict__ srb, float* __restrict__ xr){
  int b  = blockIdx.x >> 4;
  int hs = blockIdx.x & 15;
  int o  = threadIdx.x;
  float acc[16];
  #pragma unroll
  for (int m=0;m<16;++m) acc[m]=0.f;
  const float* xb = xf + b*CD;
  const float* wp = srw + o*1024;
  for (int cc=0; cc<256; cc+=8){
    float4 w4[8];
    #pragma unroll
    for (int ci=0;ci<8;++ci) w4[ci] = *(const float4*)(wp + (cc+ci)*4);   // [kh*2+kw]
    #pragma unroll
    for (int m=0;m<16;++m){
      #pragma unroll
      for (int r=0;r<2;++r){
        #pragma unroll
        for (int kw=0;kw<2;++kw){
          const float* xrow = xb + ((2*hs+r)*32 + 2*m + kw)*NBC + cc; // wave-uniform
          #pragma unroll
          for (int ci=0;ci<8;++ci){
            float wv = (r==0) ? (kw==0 ? w4[ci].x : w4[ci].y) : (kw==0 ? w4[ci].z : w4[ci].w);
            acc[m] += xrow[ci]*wv;
          }
        }
      }
    }
  }
  float bias = srb[o];
  int row0 = b*NS + hs*16;
  #pragma unroll
  for (int m=0;m<16;++m) xr[(row0+m)*CD + o] = acc[m] + bias;
}

// ---- layernorm over C, in place; 4 rows per block (1 per wave) ----
__global__ __launch_bounds__(256) void k_ln(float* __restrict__ xr, const float* __restrict__ g,
                                            const float* __restrict__ bta){
  int wv = threadIdx.x >> 6, lane = threadIdx.x & 63;
  int row = blockIdx.x*4 + wv;
  float4 v = ((const float4*)(xr + row*CD))[lane];
  float s = (v.x+v.y)+(v.z+v.w);
  #pragma unroll
  for (int off=1; off<64; off<<=1) s += __shfl_xor(s, off, 64);
  float mu = s * (1.0f/256.0f);
  float dx=v.x-mu, dy=v.y-mu, dz=v.z-mu, dw=v.w-mu;
  float s2 = (dx*dx+dy*dy)+(dz*dz+dw*dw);
  #pragma unroll
  for (int off=1; off<64; off<<=1) s2 += __shfl_xor(s2, off, 64);
  float inv = 1.0f / sqrtf(s2*(1.0f/256.0f) + 1e-5f);
  float4 gr = ((const float4*)g)[lane];
  float4 br = ((const float4*)bta)[lane];
  float4 o;
  o.x = dx*inv*gr.x + br.x;
  o.y = dy*inv*gr.y + br.y;
  o.z = dz*inv*gr.z + br.z;
  o.w = dw*inv*gr.w + br.w;
  ((float4*)(xr + row*CD))[lane] = o;
}

// ---- Q proj: q = relu(x @ Wq^T + bq) * scaling ; qb[b*1024+n][c] ----
__global__ __launch_bounds__(256) void k_qproj(const float* __restrict__ xf, const float* __restrict__ ipw,
                                               const float* __restrict__ ipb, float* __restrict__ qb){
  int b  = blockIdx.x >> 6;
  int n0 = (blockIdx.x & 63)*16;
  int o  = threadIdx.x;
  float acc[16];
  #pragma unroll
  for (int m=0;m<16;++m) acc[m]=0.f;
  const float* wp = ipw + o*CD;
  const float* xb = xf + b*CD;
  for (int cc=0; cc<256; cc+=8){
    float4 wa = *(const float4*)(wp+cc);
    float4 wb = *(const float4*)(wp+cc+4);
    float wf[8] = {wa.x,wa.y,wa.z,wa.w, wb.x,wb.y,wb.z,wb.w};
    #pragma unroll
    for (int m=0;m<16;++m){
      const float* xrow = xb + (n0+m)*NBC + cc;  // wave-uniform
      #pragma unroll
      for (int ci=0;ci<8;++ci) acc[m] += xrow[ci]*wf[ci];
    }
  }
  float bq = ipb[o];
  const float sc = 0.17677669529663687f;           // 32^-0.5
  #pragma unroll
  for (int m=0;m<16;++m)
    qb[(b*NTOK + n0 + m)*CD + o] = fmaxf(acc[m]+bq, 0.f)*sc;
}

// ---- K/V proj from xr_ln: k = relu(.+bk), v = .+bv ----
__global__ __launch_bounds__(256) void k_kvproj(const float* __restrict__ xr, const float* __restrict__ ipw,
                                                const float* __restrict__ ipb, float* __restrict__ kb,
                                                float* __restrict__ vbuf){
  int row0 = blockIdx.x*16;
  int o = threadIdx.x;
  float ak[16], av[16];
  #pragma unroll
  for (int m=0;m<16;++m){ ak[m]=0.f; av[m]=0.f; }
  const float* wkp = ipw + (CD+o)*CD;
  const float* wvp = ipw + (2*CD+o)*CD;
  for (int cc=0; cc<256; cc+=8){
    float4 ka = *(const float4*)(wkp+cc);
    float4 kb4 = *(const float4*)(wkp+cc+4);
    float4 va = *(const float4*)(wvp+cc);
    float4 vb4 = *(const float4*)(wvp+cc+4);
    float wk[8] = {ka.x,ka.y,ka.z,ka.w, kb4.x,kb4.y,kb4.z,kb4.w};
    float wv[8] = {va.x,va.y,va.z,va.w, vb4.x,vb4.y,vb4.z,vb4.w};
    #pragma unroll
    for (int m=0;m<16;++m){
      const float* xrow = xr + (row0+m)*CD + cc;   // wave-uniform
      #pragma unroll
      for (int ci=0;ci<8;++ci){ float x = xrow[ci]; ak[m] += x*wk[ci]; av[m] += x*wv[ci]; }
    }
  }
  float bk = ipb[CD+o];
  float bv = ipb[2*CD+o];
  #pragma unroll
  for (int m=0;m<16;++m){
    kb[(row0+m)*CD+o]   = fmaxf(ak[m]+bk, 0.f);
    vbuf[(row0+m)*CD+o] = av[m]+bv;
  }
}

// ---- kv[bh][d=32p+j][m] = sum_n t2_p(n) k[n,j] v[n,m]; ksum[bh][d] ----
__global__ __launch_bounds__(256) void k_kv(const float* __restrict__ kb, const float* __restrict__ vbuf,
                                            const float* __restrict__ t2, float* __restrict__ kv,
                                            float* __restrict__ ksm){
  int bh = blockIdx.x; int b = bh >> 3, h = bh & 7;
  int t = threadIdx.x; int jq = t >> 5, m = t & 31;
  float acc[4][4];
  #pragma unroll
  for (int p=0;p<4;++p){ acc[p][0]=0.f; acc[p][1]=0.f; acc[p][2]=0.f; acc[p][3]=0.f; }
  const float* kbase = kb + h*HDIM + jq*4;
  const float* vbase = vbuf + h*HDIM + m;
  for (int n=0;n<256;++n){
    int ro = (b*NS + n)*CD;
    float4 k4 = *(const float4*)(kbase + ro);
    float vv = vbase[ro];
    float4 tt = *(const float4*)(t2 + n*4);
    float tv[4] = {tt.x, tt.y, tt.z, tt.w};
    float kk[4] = {k4.x, k4.y, k4.z, k4.w};
    #pragma unroll
    for (int p=0;p<4;++p){
      float tp = tv[p]*vv;
      #pragma unroll
      for (int jj=0;jj<4;++jj) acc[p][jj] += tp*kk[jj];
    }
  }
  #pragma unroll
  for (int p=0;p<4;++p){
    #pragma unroll
    for (int jj=0;jj<4;++jj)
      kv[bh*4096 + (p*32 + jq*4 + jj)*32 + m] = acc[p][jj];
  }
  if (t < 128){
    int p = t >> 5, j = t & 31;
    float s=0.f;
    const float* kp = kb + h*HDIM + j;
    for (int n=0;n<256;++n) s += t2[n*4+p]*kp[(b*NS+n)*CD];
    ksm[bh*128 + t] = s;
  }
}

// ---- attn: per (b,h), per n: acc[m] = sum_d q_[n,d] kv[d][m]; /= clamp(denom) ----
// writes at row-major: at[(b*1024+n)*256 + h*32 + m]
__global__ __launch_bounds__(256) void k_attn(const float* __restrict__ qb, const float* __restrict__ kv,
                                              const float* __restrict__ ksm, const float* __restrict__ t1,
                                              float* __restrict__ at){
  int bh = blockIdx.x; int b = bh>>3, h = bh&7;
  const float* kvb = kv + bh*4096;
  const float* ksb = ksm + bh*128;
  for (int u=0;u<4;++u){
    int n = threadIdx.x + u*256;
    const float* qrowp = qb + (b*NTOK + n)*CD + h*HDIM;
    float4 tt = *(const float4*)(t1 + n*4);
    float tv[4] = {tt.x,tt.y,tt.z,tt.w};
    float acc[32];
    #pragma unroll
    for (int mm=0;mm<32;++mm) acc[mm]=0.f;
    float den = 0.f;
    #pragma unroll
    for (int p=0;p<4;++p){
      float tp = tv[p];
      for (int j=0;j<32;++j){
        float qq = tp*qrowp[j];
        const float* kvr = kvb + (p*32+j)*32;      // wave-uniform
        #pragma unroll
        for (int mm=0;mm<32;++mm) acc[mm] += qq*kvr[mm];
        den += qq*ksb[p*32+j];
      }
    }
    float sgn = (den>0.f) ? 1.f : ((den<0.f)? -1.f : 0.f);
    float ad = fminf(fmaxf(fabsf(den), 1e-4f), 1e4f);
    float inv = (den != 0.f) ? 1.0f/(ad*sgn) : 0.f;
    float* outb = at + (b*NTOK + n)*CD + h*HDIM;
    #pragma unroll
    for (int mq=0;mq<8;++mq){
      float4 o4 = make_float4(acc[mq*4]*inv, acc[mq*4+1]*inv, acc[mq*4+2]*inv, acc[mq*4+3]*inv);
      ((float4*)outb)[mq] = o4;
    }
  }
}

// ---- out proj + SE scale + transpose to (N,B,C) fp32 ----
__global__ __launch_bounds__(256) void k_outproj(const float* __restrict__ at, const float* __restrict__ ow,
                                                 const float* __restrict__ obv, const float* __restrict__ se,
                                                 float* __restrict__ dout){
  int row0 = blockIdx.x*16;
  int b  = row0 >> 10;
  int n0 = row0 & 1023;
  int o  = threadIdx.x;
  float acc[16];
  #pragma unroll
  for (int m=0;m<16;++m) acc[m]=0.f;
  const float* wp = ow + o*CD;
  for (int cc=0; cc<256; cc+=8){
    float4 wa = *(const float4*)(wp+cc);
    float4 wb = *(const float4*)(wp+cc+4);
    float wf[8] = {wa.x,wa.y,wa.z,wa.w, wb.x,wb.y,wb.z,wb.w};
    #pragma unroll
    for (int m=0;m<16;++m){
      const float* xrow = at + (row0+m)*CD + cc;   // wave-uniform
      #pragma unroll
      for (int ci=0;ci<8;++ci) acc[m] += xrow[ci]*wf[ci];
    }
  }
  float obo = obv[o];
  float sev = se[b*CD + o];
  #pragma unroll
  for (int m=0;m<16;++m){
    float val = (acc[m]+obo)*sev;
    dout[((n0+m)*NB + b)*CD + o] = val;
  }
}

extern "C" void kernel_launch(void* const* d_in, const int* in_sizes, int n_in,
                              void* d_out, int out_size, void* d_ws, size_t ws_size,
                              hipStream_t stream) {
  const float* query = (const float*)d_in[0];
  // d_in[1]=H, d_in[2]=W (fixed 32x32), d_in[3]=key, d_in[4]=value unused by reference
  const float* ipw = (const float*)d_in[5];
  const float* ipb = (const float*)d_in[6];
  const float* srw = (const float*)d_in[7];
  const float* srb = (const float*)d_in[8];
  const float* ng  = (const float*)d_in[9];
  const float* nbb = (const float*)d_in[10];
  const float* ow  = (const float*)d_in[11];
  const float* obv = (const float*)d_in[12];
  const float* sw1 = (const float*)d_in[13];
  const float* sw2 = (const float*)d_in[14];
  float* dout = (float*)d_out;
  float* ws = (float*)d_ws;

  float* qbuf = ws;                 // 16,777,216 f  (q, [b*1024+n][c])
  float* at   = ws + 16777216;      // 16,777,216 f  (attn, [b*1024+n][c])
  float* xr   = ws + 33554432;      //  4,194,304 f  (conv out -> LN in place, [b*256+m][c])
  float* kb   = ws + 37748736;      //  4,194,304 f
  float* vb   = ws + 41943040;      //  4,194,304 f
  float* kv   = ws + 46137344;      //  2,097,152 f  ([bh][128][32])
  float* ks   = ws + 48234496;      //     65,536 f
  float* part = ws + 48300032;      //     65,536 f
  float* se   = ws + 48365568;      //     16,384 f
  float* t1   = ws + 48381952;      //      4,096 f
  float* t2   = ws + 48386048;      //      1,024 f

  k_trig  <<<4,    256,0,stream>>>(t1, t2);
  k_semean<<<256,  256,0,stream>>>(query, part);
  k_semlp <<<64,   256,0,stream>>>(part, sw1, sw2, se);
  k_conv  <<<1024, 256,0,stream>>>(query, srw, srb, xr);
  k_ln    <<<4096, 256,0,stream>>>(xr, ng, nbb);
  k_kvproj<<<1024, 256,0,stream>>>(xr, ipw, ipb, kb, vb);
  k_qproj <<<4096, 256,0,stream>>>(query, ipw, ipb, qbuf);
  k_kv    <<<512,  256,0,stream>>>(kb, vb, t2, kv, ks);
  k_attn  <<<512,  256,0,stream>>>(qbuf, kv, ks, t1, at);
  k_outproj<<<4096,256,0,stream>>>(at, ow, obv, se, dout);
}